// Round 1
// baseline (885.812 us; speedup 1.0000x reference)
//
#include <hip/hip_runtime.h>
#include <hip/hip_bf16.h>
#include <math.h>

#define V 32000
#define H 1024
#define B 64
#define T 1024

typedef __bf16 bf16x8 __attribute__((ext_vector_type(8)));
typedef float  f32x4  __attribute__((ext_vector_type(4)));

__device__ __forceinline__ unsigned short f2bf(float f) {
    unsigned int u = __float_as_uint(f);
    u += 0x7fffu + ((u >> 16) & 1u);          // round-to-nearest-even
    return (unsigned short)(u >> 16);
}

// ---------------------------------------------------------------------------
// K1: embedding gather + GRU cell. h_new[64][1024] -> hid (d_out hidden slot)
// grid 256 blocks x 256 thr; wave = one output column k, lane = batch.
// ---------------------------------------------------------------------------
__global__ __launch_bounds__(256) void k1_gru(
    const int* __restrict__ idx, const float* __restrict__ lasth,
    const float* __restrict__ emb, const float* __restrict__ w_ih,
    const float* __restrict__ w_hh, const float* __restrict__ b_ih,
    const float* __restrict__ b_hh, float* __restrict__ hnew)
{
    __shared__ float lx[64][129];   // pad +1: lane-row reads are 2-way (free)
    __shared__ float lh[64][129];
    const int tid  = threadIdx.x;
    const int lane = tid & 63;
    const int wv   = tid >> 6;
    int k  = blockIdx.x * 4 + wv;
    int kk = __builtin_amdgcn_readfirstlane(k);   // force scalar (s_load) weight streams
    const float* wxr = w_ih + (size_t)kk * H;
    const float* wxz = w_ih + (size_t)(kk + H) * H;
    const float* wxn = w_ih + (size_t)(kk + 2 * H) * H;
    const float* whr = w_hh + (size_t)kk * H;
    const float* whz = w_hh + (size_t)(kk + H) * H;
    const float* whn = w_hh + (size_t)(kk + 2 * H) * H;

    float axr = 0.f, axz = 0.f, axn = 0.f, ahr = 0.f, ahz = 0.f, ahn = 0.f;

    for (int c = 0; c < H; c += 128) {
        __syncthreads();
        // cooperative stage: 64 rows x 128 cols, float4 global loads
        for (int i = tid; i < 64 * 32; i += 256) {
            int r  = i >> 5;
            int c4 = (i & 31) << 2;
            int row = idx[r];
            float4 xv = *(const float4*)(emb + (size_t)row * H + c + c4);
            float4 hv = *(const float4*)(lasth + (size_t)r * H + c + c4);
            lx[r][c4] = xv.x; lx[r][c4 + 1] = xv.y; lx[r][c4 + 2] = xv.z; lx[r][c4 + 3] = xv.w;
            lh[r][c4] = hv.x; lh[r][c4 + 1] = hv.y; lh[r][c4 + 2] = hv.z; lh[r][c4 + 3] = hv.w;
        }
        __syncthreads();
        #pragma unroll 4
        for (int h = 0; h < 128; ++h) {
            float xv = lx[lane][h];
            float hv = lh[lane][h];
            axr = fmaf(xv, wxr[c + h], axr);
            axz = fmaf(xv, wxz[c + h], axz);
            axn = fmaf(xv, wxn[c + h], axn);
            ahr = fmaf(hv, whr[c + h], ahr);
            ahz = fmaf(hv, whz[c + h], ahz);
            ahn = fmaf(hv, whn[c + h], ahn);
        }
    }
    float xr = axr + b_ih[kk];
    float xz = axz + b_ih[kk + H];
    float xn = axn + b_ih[kk + 2 * H];
    float hr = ahr + b_hh[kk];
    float hz = ahz + b_hh[kk + H];
    float hn = ahn + b_hh[kk + 2 * H];
    float r = 1.f / (1.f + __expf(-(xr + hr)));
    float z = 1.f / (1.f + __expf(-(xz + hz)));
    float n = tanhf(xn + r * hn);
    float hprev = lasth[(size_t)lane * H + kk];
    hnew[(size_t)lane * H + kk] = (1.f - z) * n + z * hprev;
}

// ---------------------------------------------------------------------------
// K2: fused attention pass 1 — scores + online-softmax partial context.
// Single read of encoder_outputs (256 MB). Wave = (b, 64-t chunk), lane covers H.
// grid 256 blocks x 256 thr (4 waves => 16 chunks/b).
// ---------------------------------------------------------------------------
__device__ __forceinline__ void k2_load(float4 (&buf)[2][4], const float* encb,
                                        int t0, int gi, int lane)
{
    int tbase = t0 + gi * 2;
    #pragma unroll
    for (int u = 0; u < 2; ++u) {
        int t = tbase + u; if (t > T - 1) t = T - 1;   // clamp (epilogue prefetch)
        const float* p = encb + (size_t)t * (B * H);
        #pragma unroll
        for (int j = 0; j < 4; ++j)
            buf[u][j] = *(const float4*)(p + ((j * 64 + lane) << 2));
    }
}

__device__ __forceinline__ void k2_proc(const float4 (&buf)[2][4], float4 (&ctx)[4],
                                        float& m, float& l, float& myscore,
                                        const float4 (&hq)[4], int gi, int lane)
{
    #pragma unroll
    for (int u = 0; u < 2; ++u) {
        float d = 0.f;
        #pragma unroll
        for (int j = 0; j < 4; ++j) {
            d = fmaf(hq[j].x, buf[u][j].x, d);
            d = fmaf(hq[j].y, buf[u][j].y, d);
            d = fmaf(hq[j].z, buf[u][j].z, d);
            d = fmaf(hq[j].w, buf[u][j].w, d);
        }
        #pragma unroll
        for (int off = 1; off < 64; off <<= 1) d += __shfl_xor(d, off, 64);
        float mn = fmaxf(m, d);
        float al = __expf(m - mn);   // m=-inf first iter -> 0, correct
        float p  = __expf(d - mn);
        l = fmaf(l, al, p);
        #pragma unroll
        for (int j = 0; j < 4; ++j) {
            ctx[j].x = fmaf(ctx[j].x, al, p * buf[u][j].x);
            ctx[j].y = fmaf(ctx[j].y, al, p * buf[u][j].y);
            ctx[j].z = fmaf(ctx[j].z, al, p * buf[u][j].z);
            ctx[j].w = fmaf(ctx[j].w, al, p * buf[u][j].w);
        }
        m = mn;
        if (lane == gi * 2 + u) myscore = d;
    }
}

__global__ __launch_bounds__(256) void k2_attn(
    const float* __restrict__ hnew, const float* __restrict__ enc,
    float* __restrict__ scores, float* __restrict__ pm,
    float* __restrict__ pl, float* __restrict__ pctx)
{
    const int tid  = threadIdx.x;
    const int lane = tid & 63;
    const int wv   = tid >> 6;
    const int b     = blockIdx.x >> 2;
    const int chunk = ((blockIdx.x & 3) << 2) | wv;   // 0..15
    const int t0    = chunk * 64;
    const float* encb = enc + (size_t)b * H;

    float4 hq[4];
    #pragma unroll
    for (int j = 0; j < 4; ++j)
        hq[j] = *(const float4*)(hnew + (size_t)b * H + ((j * 64 + lane) << 2));

    float4 ctx[4];
    #pragma unroll
    for (int j = 0; j < 4; ++j) { ctx[j].x = 0.f; ctx[j].y = 0.f; ctx[j].z = 0.f; ctx[j].w = 0.f; }
    float m = -INFINITY, l = 0.f, myscore = 0.f;

    float4 bufA[2][4], bufB[2][4];
    k2_load(bufA, encb, t0, 0, lane);
    for (int g = 0; g < 32; g += 2) {
        k2_load(bufB, encb, t0, g + 1, lane);
        k2_proc(bufA, ctx, m, l, myscore, hq, g, lane);
        k2_load(bufA, encb, t0, g + 2, lane);
        k2_proc(bufB, ctx, m, l, myscore, hq, g + 1, lane);
    }

    scores[(size_t)b * T + t0 + lane] = myscore;
    if (lane == 0) { pm[b * 16 + chunk] = m; pl[b * 16 + chunk] = l; }
    float* pc = pctx + ((size_t)(b * 16 + chunk) << 10);
    #pragma unroll
    for (int j = 0; j < 4; ++j)
        *(float4*)(pc + ((j * 64 + lane) << 2)) = ctx[j];
}

// ---------------------------------------------------------------------------
// K3: combine partials -> context[64][1024] + attn weights output.
// grid 64 blocks (one per b) x 256 thr.
// ---------------------------------------------------------------------------
__global__ __launch_bounds__(256) void k3_combine(
    const float* __restrict__ scores, const float* __restrict__ pm,
    const float* __restrict__ pl, const float* __restrict__ pctx,
    float* __restrict__ ctxo, float* __restrict__ att)
{
    const int b = blockIdx.x, tid = threadIdx.x;
    float ms = -INFINITY;
    #pragma unroll
    for (int c = 0; c < 16; ++c) ms = fmaxf(ms, pm[b * 16 + c]);
    float w[16]; float ls = 0.f;
    #pragma unroll
    for (int c = 0; c < 16; ++c) {
        w[c] = __expf(pm[b * 16 + c] - ms);
        ls = fmaf(pl[b * 16 + c], w[c], ls);
    }
    float inv = 1.f / ls;

    float4 acc; acc.x = acc.y = acc.z = acc.w = 0.f;
    const float* pc = pctx + ((size_t)b * 16 << 10) + tid * 4;
    #pragma unroll
    for (int c = 0; c < 16; ++c) {
        float4 v = *(const float4*)(pc + c * 1024);
        acc.x = fmaf(v.x, w[c], acc.x);
        acc.y = fmaf(v.y, w[c], acc.y);
        acc.z = fmaf(v.z, w[c], acc.z);
        acc.w = fmaf(v.w, w[c], acc.w);
    }
    acc.x *= inv; acc.y *= inv; acc.z *= inv; acc.w *= inv;
    *(float4*)(ctxo + (size_t)b * H + tid * 4) = acc;

    float4 s = *(const float4*)(scores + (size_t)b * T + tid * 4);
    float4 a;
    a.x = __expf(s.x - ms) * inv;
    a.y = __expf(s.y - ms) * inv;
    a.z = __expf(s.z - ms) * inv;
    a.w = __expf(s.w - ms) * inv;
    *(float4*)(att + (size_t)b * T + tid * 4) = a;
}

// ---------------------------------------------------------------------------
// K4: concat_output = tanh([h_new | ctx] @ concat_W^T + concat_b)
// same structure as K1. grid 256 x 256.
// ---------------------------------------------------------------------------
__global__ __launch_bounds__(256) void k4_concat(
    const float* __restrict__ hnew, const float* __restrict__ ctx,
    const float* __restrict__ cW, const float* __restrict__ cb,
    float* __restrict__ cout_)
{
    __shared__ float lh[64][129];
    __shared__ float lc[64][129];
    const int tid = threadIdx.x, lane = tid & 63, wv = tid >> 6;
    int k  = blockIdx.x * 4 + wv;
    int kk = __builtin_amdgcn_readfirstlane(k);
    const float* w0 = cW + (size_t)kk * 2048;
    const float* w1 = w0 + 1024;
    float acc = 0.f;
    for (int c = 0; c < H; c += 128) {
        __syncthreads();
        for (int i = tid; i < 64 * 32; i += 256) {
            int r  = i >> 5;
            int c4 = (i & 31) << 2;
            float4 hv = *(const float4*)(hnew + (size_t)r * H + c + c4);
            float4 cv = *(const float4*)(ctx  + (size_t)r * H + c + c4);
            lh[r][c4] = hv.x; lh[r][c4 + 1] = hv.y; lh[r][c4 + 2] = hv.z; lh[r][c4 + 3] = hv.w;
            lc[r][c4] = cv.x; lc[r][c4 + 1] = cv.y; lc[r][c4 + 2] = cv.z; lc[r][c4 + 3] = cv.w;
        }
        __syncthreads();
        #pragma unroll 4
        for (int h = 0; h < 128; ++h) {
            acc = fmaf(lh[lane][h], w0[c + h], acc);
            acc = fmaf(lc[lane][h], w1[c + h], acc);
        }
    }
    cout_[(size_t)lane * H + kk] = tanhf(acc + cb[kk]);
}

// ---------------------------------------------------------------------------
// K5: output = concat_output @ out_W^T + out_b via bf16 MFMA (fp32 acc).
// 64x64 block tile, K-chunks of 128 staged fp32->bf16 in LDS. grid 500 x 256.
// ---------------------------------------------------------------------------
__global__ __launch_bounds__(256) void k5_proj(
    const float* __restrict__ A, const float* __restrict__ Wt,
    const float* __restrict__ bias, float* __restrict__ out)
{
    __shared__ unsigned short lA[64][136];   // +8 bf16 pad -> b128 reads 2-way (free)
    __shared__ unsigned short lB[64][136];
    const int tid = threadIdx.x, lane = tid & 63, wv = tid >> 6;
    const int n0 = blockIdx.x * 64;

    f32x4 acc[4];
    #pragma unroll
    for (int j = 0; j < 4; ++j) acc[j] = (f32x4){0.f, 0.f, 0.f, 0.f};

    const int arow = (wv << 4) + (lane & 15);
    const int kofs = (lane >> 4) << 3;

    for (int kc = 0; kc < H; kc += 128) {
        __syncthreads();
        for (int i = tid; i < 64 * 32; i += 256) {
            int r  = i >> 5;
            int c4 = (i & 31) << 2;
            float4 va = *(const float4*)(A  + (size_t)r * H + kc + c4);
            float4 vb = *(const float4*)(Wt + (size_t)(n0 + r) * H + kc + c4);
            ushort4 pa, pb;
            pa.x = f2bf(va.x); pa.y = f2bf(va.y); pa.z = f2bf(va.z); pa.w = f2bf(va.w);
            pb.x = f2bf(vb.x); pb.y = f2bf(vb.y); pb.z = f2bf(vb.z); pb.w = f2bf(vb.w);
            *(ushort4*)&lA[r][c4] = pa;
            *(ushort4*)&lB[r][c4] = pb;
        }
        __syncthreads();
        #pragma unroll
        for (int ks = 0; ks < 128; ks += 32) {
            int col = ks + kofs;
            bf16x8 a = *(const bf16x8*)&lA[arow][col];
            #pragma unroll
            for (int j = 0; j < 4; ++j) {
                bf16x8 bb = *(const bf16x8*)&lB[(j << 4) + (lane & 15)][col];
                acc[j] = __builtin_amdgcn_mfma_f32_16x16x32_bf16(a, bb, acc[j], 0, 0, 0);
            }
        }
    }

    const int nbase = n0 + (lane & 15);
    const int mbase = (wv << 4) + ((lane >> 4) << 2);
    #pragma unroll
    for (int j = 0; j < 4; ++j) {
        int v = nbase + (j << 4);
        float bv = bias[v];
        #pragma unroll
        for (int r = 0; r < 4; ++r)
            out[(size_t)(mbase + r) * V + v] = acc[j][r] + bv;
    }
}

// ---------------------------------------------------------------------------
// d_out layout (floats): [0, 2048000) output | [2048000, +65536) hidden |
// [2113536, +65536) attn. Front of output region doubles as scratch until K5:
//   scores @0 (65536), pm @65536 (1024), pl @66560 (1024),
//   pctx @67584 (1048576), ctx @1116160 (65536).
// d_ws: concat_output (65536 floats) — K5 reads it while overwriting d_out.
// ---------------------------------------------------------------------------
extern "C" void kernel_launch(void* const* d_in, const int* in_sizes, int n_in,
                              void* d_out, int out_size, void* d_ws, size_t ws_size,
                              hipStream_t stream) {
    const int*   idx   = (const int*)d_in[0];
    const float* lasth = (const float*)d_in[1];
    const float* enc   = (const float*)d_in[2];
    const float* emb   = (const float*)d_in[3];
    const float* w_ih  = (const float*)d_in[4];
    const float* w_hh  = (const float*)d_in[5];
    const float* b_ih  = (const float*)d_in[6];
    const float* b_hh  = (const float*)d_in[7];
    const float* cW    = (const float*)d_in[8];
    const float* cb    = (const float*)d_in[9];
    const float* oW    = (const float*)d_in[10];
    const float* ob    = (const float*)d_in[11];

    float* out = (float*)d_out;
    float* hid = out + 2048000;
    float* att = hid + 65536;
    float* scores = out;
    float* pm     = out + 65536;
    float* pl     = out + 66560;
    float* pctx   = out + 67584;
    float* ctx    = out + 1116160;
    float* cout_  = (float*)d_ws;   // 256 KB

    k1_gru<<<256, 256, 0, stream>>>(idx, lasth, emb, w_ih, w_hh, b_ih, b_hh, hid);
    k2_attn<<<256, 256, 0, stream>>>(hid, enc, scores, pm, pl, pctx);
    k3_combine<<<64, 256, 0, stream>>>(scores, pm, pl, pctx, ctx, att);
    k4_concat<<<256, 256, 0, stream>>>(hid, ctx, cW, cb, cout_);
    k5_proj<<<500, 256, 0, stream>>>(cout_, oW, ob, out);
}

// Round 2
// 597.884 us; speedup vs baseline: 1.4816x; 1.4816x over previous
//
#include <hip/hip_runtime.h>
#include <hip/hip_bf16.h>
#include <math.h>

#define V 32000
#define H 1024
#define B 64
#define T 1024

typedef __bf16 bf16x8 __attribute__((ext_vector_type(8)));
typedef float  f32x4  __attribute__((ext_vector_type(4)));

__device__ __forceinline__ unsigned short f2bf(float f) {
    unsigned int u = __float_as_uint(f);
    u += 0x7fffu + ((u >> 16) & 1u);          // round-to-nearest-even
    return (unsigned short)(u >> 16);
}

// ---------------------------------------------------------------------------
// K1a: split-K fp32 GEMM for both GRU input GEMMs.
//   z=0: gx = gather(emb,idx)[64,1024] @ w_ih^T -> [64,3072]
//   z=1: gh = lasth[64,1024]           @ w_hh^T -> [64,3072]
// grid (48 n-tiles, 4 h-groups of 256, 2 z) x 256 thr.
// partials: part[(z*4+hg)*64 + m][3072]
// ---------------------------------------------------------------------------
__global__ __launch_bounds__(256) void k1a_gemm(
    const int* __restrict__ idx, const float* __restrict__ lasth,
    const float* __restrict__ emb, const float* __restrict__ w_ih,
    const float* __restrict__ w_hh, float* __restrict__ part)
{
    __shared__ float xs[64][68];   // x natural layout [b][h]
    __shared__ float ws[64][68];   // w transposed     [h][n]
    const int tid = threadIdx.x;
    const int n0  = blockIdx.x * 64;
    const int hg  = blockIdx.y;
    const int z   = blockIdx.z;
    const float* Wm = z ? w_hh : w_ih;
    const int tk4 = (tid & 15) << 2;
    const int tb4 = (tid >> 4) << 2;

    f32x4 acc[4];
    #pragma unroll
    for (int i = 0; i < 4; ++i) acc[i] = (f32x4){0.f, 0.f, 0.f, 0.f};

    for (int c = 0; c < 4; ++c) {
        const int hb = hg * 256 + c * 64;
        __syncthreads();
        #pragma unroll
        for (int it = 0; it < 4; ++it) {
            int i  = tid + it * 256;
            int r  = i >> 4;
            int c4 = (i & 15) << 2;
            const float* xrow = z ? (lasth + (size_t)r * H)
                                  : (emb + (size_t)idx[r] * H);
            *(float4*)&xs[r][c4] = *(const float4*)(xrow + hb + c4);
            float4 wv = *(const float4*)(Wm + (size_t)(n0 + r) * H + hb + c4);
            ws[c4 + 0][r] = wv.x; ws[c4 + 1][r] = wv.y;
            ws[c4 + 2][r] = wv.z; ws[c4 + 3][r] = wv.w;
        }
        __syncthreads();
        #pragma unroll
        for (int h = 0; h < 64; h += 4) {
            f32x4 w0 = *(const f32x4*)&ws[h + 0][tk4];
            f32x4 w1 = *(const f32x4*)&ws[h + 1][tk4];
            f32x4 w2 = *(const f32x4*)&ws[h + 2][tk4];
            f32x4 w3 = *(const f32x4*)&ws[h + 3][tk4];
            #pragma unroll
            for (int i2 = 0; i2 < 4; ++i2) {
                f32x4 xv = *(const f32x4*)&xs[tb4 + i2][h];
                acc[i2] += xv.x * w0;
                acc[i2] += xv.y * w1;
                acc[i2] += xv.z * w2;
                acc[i2] += xv.w * w3;
            }
        }
    }
    #pragma unroll
    for (int i2 = 0; i2 < 4; ++i2)
        *(f32x4*)&part[((size_t)((z * 4 + hg) * 64 + tb4 + i2)) * 3072 + n0 + tk4] = acc[i2];
}

// ---------------------------------------------------------------------------
// K1b: combine partials + biases -> GRU activation -> h_new
// ---------------------------------------------------------------------------
__global__ __launch_bounds__(256) void k1b_act(
    const float* __restrict__ part, const float* __restrict__ lasth,
    const float* __restrict__ b_ih, const float* __restrict__ b_hh,
    float* __restrict__ hnew)
{
    int gid = blockIdx.x * 256 + threadIdx.x;
    int m = gid >> 10, k = gid & 1023;
    float xr = 0.f, xz = 0.f, xn = 0.f, hr = 0.f, hz = 0.f, hn = 0.f;
    #pragma unroll
    for (int g = 0; g < 4; ++g) {
        const float* px = part + ((size_t)(g * 64 + m)) * 3072 + k;
        const float* ph = part + ((size_t)((4 + g) * 64 + m)) * 3072 + k;
        xr += px[0]; xz += px[1024]; xn += px[2048];
        hr += ph[0]; hz += ph[1024]; hn += ph[2048];
    }
    xr += b_ih[k]; xz += b_ih[k + H]; xn += b_ih[k + 2 * H];
    hr += b_hh[k]; hz += b_hh[k + H]; hn += b_hh[k + 2 * H];
    float r = 1.f / (1.f + __expf(-(xr + hr)));
    float z = 1.f / (1.f + __expf(-(xz + hz)));
    float n = tanhf(xn + r * hn);
    float hprev = lasth[(size_t)m * H + k];
    hnew[(size_t)m * H + k] = (1.f - z) * n + z * hprev;
}

// ---------------------------------------------------------------------------
// K2: fused attention pass 1 — scores + online-softmax partial context.
// Wave = (b, 64-t chunk); groups of 4 timesteps, 16 float4 in flight.
// ---------------------------------------------------------------------------
__device__ __forceinline__ void k2_load4(float4 (&buf)[4][4], const float* encb,
                                         int t0, int g, int lane)
{
    int tb = t0 + g * 4;
    #pragma unroll
    for (int u = 0; u < 4; ++u) {
        const float* p = encb + (size_t)(tb + u) * (B * H);
        #pragma unroll
        for (int j = 0; j < 4; ++j)
            buf[u][j] = *(const float4*)(p + j * 256 + lane * 4);
    }
}

__device__ __forceinline__ void k2_proc4(const float4 (&buf)[4][4], float4 (&ctx)[4],
                                         float& m, float& l, float& myscore,
                                         const float4 (&hq)[4], int g, int lane)
{
    #pragma unroll
    for (int u = 0; u < 4; ++u) {
        float d = 0.f;
        #pragma unroll
        for (int j = 0; j < 4; ++j) {
            d = fmaf(hq[j].x, buf[u][j].x, d);
            d = fmaf(hq[j].y, buf[u][j].y, d);
            d = fmaf(hq[j].z, buf[u][j].z, d);
            d = fmaf(hq[j].w, buf[u][j].w, d);
        }
        #pragma unroll
        for (int off = 1; off < 64; off <<= 1) d += __shfl_xor(d, off, 64);
        float mn = fmaxf(m, d);
        float al = __expf(m - mn);
        float p  = __expf(d - mn);
        l = fmaf(l, al, p);
        #pragma unroll
        for (int j = 0; j < 4; ++j) {
            ctx[j].x = fmaf(ctx[j].x, al, p * buf[u][j].x);
            ctx[j].y = fmaf(ctx[j].y, al, p * buf[u][j].y);
            ctx[j].z = fmaf(ctx[j].z, al, p * buf[u][j].z);
            ctx[j].w = fmaf(ctx[j].w, al, p * buf[u][j].w);
        }
        m = mn;
        if (lane == g * 4 + u) myscore = d;
    }
}

__global__ __launch_bounds__(256) void k2_attn(
    const float* __restrict__ hnew, const float* __restrict__ enc,
    float* __restrict__ scores, float* __restrict__ pm,
    float* __restrict__ pl, float* __restrict__ pctx)
{
    const int tid  = threadIdx.x;
    const int lane = tid & 63;
    const int wv   = tid >> 6;
    const int b     = blockIdx.x >> 2;
    const int chunk = ((blockIdx.x & 3) << 2) | wv;   // 0..15
    const int t0    = chunk * 64;
    const float* encb = enc + (size_t)b * H;

    float4 hq[4];
    #pragma unroll
    for (int j = 0; j < 4; ++j)
        hq[j] = *(const float4*)(hnew + (size_t)b * H + j * 256 + lane * 4);

    float4 ctx[4];
    #pragma unroll
    for (int j = 0; j < 4; ++j) { ctx[j].x = 0.f; ctx[j].y = 0.f; ctx[j].z = 0.f; ctx[j].w = 0.f; }
    float m = -INFINITY, l = 0.f, myscore = 0.f;

    float4 bufA[4][4], bufB[4][4];
    k2_load4(bufA, encb, t0, 0, lane);
    k2_load4(bufB, encb, t0, 1, lane);
    for (int g = 0; g < 14; g += 2) {
        k2_proc4(bufA, ctx, m, l, myscore, hq, g, lane);
        k2_load4(bufA, encb, t0, g + 2, lane);
        k2_proc4(bufB, ctx, m, l, myscore, hq, g + 1, lane);
        k2_load4(bufB, encb, t0, g + 3, lane);
    }
    k2_proc4(bufA, ctx, m, l, myscore, hq, 14, lane);
    k2_proc4(bufB, ctx, m, l, myscore, hq, 15, lane);

    scores[(size_t)b * T + t0 + lane] = myscore;
    if (lane == 0) { pm[b * 16 + chunk] = m; pl[b * 16 + chunk] = l; }
    float* pc = pctx + ((size_t)(b * 16 + chunk) << 10);
    #pragma unroll
    for (int j = 0; j < 4; ++j)
        *(float4*)(pc + j * 256 + lane * 4) = ctx[j];
}

// ---------------------------------------------------------------------------
// K3: combine partials -> context[64][1024] + attn weights output.
// ---------------------------------------------------------------------------
__global__ __launch_bounds__(256) void k3_combine(
    const float* __restrict__ scores, const float* __restrict__ pm,
    const float* __restrict__ pl, const float* __restrict__ pctx,
    float* __restrict__ ctxo, float* __restrict__ att)
{
    const int b = blockIdx.x, tid = threadIdx.x;
    float ms = -INFINITY;
    #pragma unroll
    for (int c = 0; c < 16; ++c) ms = fmaxf(ms, pm[b * 16 + c]);
    float w[16]; float ls = 0.f;
    #pragma unroll
    for (int c = 0; c < 16; ++c) {
        w[c] = __expf(pm[b * 16 + c] - ms);
        ls = fmaf(pl[b * 16 + c], w[c], ls);
    }
    float inv = 1.f / ls;

    float4 acc; acc.x = acc.y = acc.z = acc.w = 0.f;
    const float* pc = pctx + ((size_t)b * 16 << 10) + tid * 4;
    #pragma unroll
    for (int c = 0; c < 16; ++c) {
        float4 v = *(const float4*)(pc + c * 1024);
        acc.x = fmaf(v.x, w[c], acc.x);
        acc.y = fmaf(v.y, w[c], acc.y);
        acc.z = fmaf(v.z, w[c], acc.z);
        acc.w = fmaf(v.w, w[c], acc.w);
    }
    acc.x *= inv; acc.y *= inv; acc.z *= inv; acc.w *= inv;
    *(float4*)(ctxo + (size_t)b * H + tid * 4) = acc;

    float4 s = *(const float4*)(scores + (size_t)b * T + tid * 4);
    float4 a;
    a.x = __expf(s.x - ms) * inv;
    a.y = __expf(s.y - ms) * inv;
    a.z = __expf(s.z - ms) * inv;
    a.w = __expf(s.w - ms) * inv;
    *(float4*)(att + (size_t)b * T + tid * 4) = a;
}

// ---------------------------------------------------------------------------
// K4a: split-K fp32 GEMM: [h_new | ctx][64,2048] @ concat_W^T -> [64,1024]
// grid (16 n-tiles, 4 h-groups of 512) x 256. partials pc[hg*64+m][1024]
// ---------------------------------------------------------------------------
__global__ __launch_bounds__(256) void k4a_gemm(
    const float* __restrict__ hnew, const float* __restrict__ ctxv,
    const float* __restrict__ cW, float* __restrict__ pc)
{
    __shared__ float xs[64][68];
    __shared__ float ws[64][68];
    const int tid = threadIdx.x;
    const int n0  = blockIdx.x * 64;
    const int hg  = blockIdx.y;
    const float* X = (hg < 2) ? hnew : ctxv;
    const int xoff = (hg & 1) * 512;
    const int tk4 = (tid & 15) << 2;
    const int tb4 = (tid >> 4) << 2;

    f32x4 acc[4];
    #pragma unroll
    for (int i = 0; i < 4; ++i) acc[i] = (f32x4){0.f, 0.f, 0.f, 0.f};

    for (int c = 0; c < 8; ++c) {
        const int hbw = hg * 512 + c * 64;     // into cW rows (stride 2048)
        const int hbx = xoff + c * 64;         // into X rows (stride 1024)
        __syncthreads();
        #pragma unroll
        for (int it = 0; it < 4; ++it) {
            int i  = tid + it * 256;
            int r  = i >> 4;
            int c4 = (i & 15) << 2;
            *(float4*)&xs[r][c4] = *(const float4*)(X + (size_t)r * H + hbx + c4);
            float4 wv = *(const float4*)(cW + (size_t)(n0 + r) * 2048 + hbw + c4);
            ws[c4 + 0][r] = wv.x; ws[c4 + 1][r] = wv.y;
            ws[c4 + 2][r] = wv.z; ws[c4 + 3][r] = wv.w;
        }
        __syncthreads();
        #pragma unroll
        for (int h = 0; h < 64; h += 4) {
            f32x4 w0 = *(const f32x4*)&ws[h + 0][tk4];
            f32x4 w1 = *(const f32x4*)&ws[h + 1][tk4];
            f32x4 w2 = *(const f32x4*)&ws[h + 2][tk4];
            f32x4 w3 = *(const f32x4*)&ws[h + 3][tk4];
            #pragma unroll
            for (int i2 = 0; i2 < 4; ++i2) {
                f32x4 xv = *(const f32x4*)&xs[tb4 + i2][h];
                acc[i2] += xv.x * w0;
                acc[i2] += xv.y * w1;
                acc[i2] += xv.z * w2;
                acc[i2] += xv.w * w3;
            }
        }
    }
    #pragma unroll
    for (int i2 = 0; i2 < 4; ++i2)
        *(f32x4*)&pc[((size_t)(hg * 64 + tb4 + i2)) * 1024 + n0 + tk4] = acc[i2];
}

// K4b: combine + bias + tanh -> concat_output (fp32, d_ws)
__global__ __launch_bounds__(256) void k4b_act(
    const float* __restrict__ pc, const float* __restrict__ cb,
    float* __restrict__ cout_)
{
    int gid = blockIdx.x * 256 + threadIdx.x;
    int m = gid >> 10, n = gid & 1023;
    float a = cb[n];
    #pragma unroll
    for (int g = 0; g < 4; ++g)
        a += pc[((size_t)(g * 64 + m)) * 1024 + n];
    cout_[(size_t)m * H + n] = tanhf(a);
}

// ---------------------------------------------------------------------------
// K5: output = concat_output @ out_W^T + out_b via bf16 MFMA (fp32 acc).
// ---------------------------------------------------------------------------
__global__ __launch_bounds__(256) void k5_proj(
    const float* __restrict__ A, const float* __restrict__ Wt,
    const float* __restrict__ bias, float* __restrict__ out)
{
    __shared__ unsigned short lA[64][136];
    __shared__ unsigned short lB[64][136];
    const int tid = threadIdx.x, lane = tid & 63, wv = tid >> 6;
    const int n0 = blockIdx.x * 64;

    f32x4 acc[4];
    #pragma unroll
    for (int j = 0; j < 4; ++j) acc[j] = (f32x4){0.f, 0.f, 0.f, 0.f};

    const int arow = (wv << 4) + (lane & 15);
    const int kofs = (lane >> 4) << 3;

    for (int kc = 0; kc < H; kc += 128) {
        __syncthreads();
        for (int i = tid; i < 64 * 32; i += 256) {
            int r  = i >> 5;
            int c4 = (i & 31) << 2;
            float4 va = *(const float4*)(A  + (size_t)r * H + kc + c4);
            float4 vb = *(const float4*)(Wt + (size_t)(n0 + r) * H + kc + c4);
            ushort4 pa, pb;
            pa.x = f2bf(va.x); pa.y = f2bf(va.y); pa.z = f2bf(va.z); pa.w = f2bf(va.w);
            pb.x = f2bf(vb.x); pb.y = f2bf(vb.y); pb.z = f2bf(vb.z); pb.w = f2bf(vb.w);
            *(ushort4*)&lA[r][c4] = pa;
            *(ushort4*)&lB[r][c4] = pb;
        }
        __syncthreads();
        #pragma unroll
        for (int ks = 0; ks < 128; ks += 32) {
            int col = ks + kofs;
            bf16x8 a = *(const bf16x8*)&lA[arow][col];
            #pragma unroll
            for (int j = 0; j < 4; ++j) {
                bf16x8 bb = *(const bf16x8*)&lB[(j << 4) + (lane & 15)][col];
                acc[j] = __builtin_amdgcn_mfma_f32_16x16x32_bf16(a, bb, acc[j], 0, 0, 0);
            }
        }
    }

    const int nbase = n0 + (lane & 15);
    const int mbase = (wv << 4) + ((lane >> 4) << 2);
    #pragma unroll
    for (int j = 0; j < 4; ++j) {
        int v = nbase + (j << 4);
        float bv = bias[v];
        #pragma unroll
        for (int r = 0; r < 4; ++r)
            out[(size_t)(mbase + r) * V + v] = acc[j][r] + bv;
    }
}

// ---------------------------------------------------------------------------
// d_out float layout: [0, 2048000) output | [2048000,+65536) hidden |
// [2113536,+65536) attn. Scratch (sequential lifetimes, all in output region):
//   phase1: pg @0 (1572864)
//   phase2: scores @0 (65536), pm @65536, pl @66560, pctx @67584 (1048576),
//           ctx @1116160 (65536), pc @1181696 (262144)
// d_ws: concat_output (65536 floats).
// ---------------------------------------------------------------------------
extern "C" void kernel_launch(void* const* d_in, const int* in_sizes, int n_in,
                              void* d_out, int out_size, void* d_ws, size_t ws_size,
                              hipStream_t stream) {
    const int*   idx   = (const int*)d_in[0];
    const float* lasth = (const float*)d_in[1];
    const float* enc   = (const float*)d_in[2];
    const float* emb   = (const float*)d_in[3];
    const float* w_ih  = (const float*)d_in[4];
    const float* w_hh  = (const float*)d_in[5];
    const float* b_ih  = (const float*)d_in[6];
    const float* b_hh  = (const float*)d_in[7];
    const float* cW    = (const float*)d_in[8];
    const float* cb    = (const float*)d_in[9];
    const float* oW    = (const float*)d_in[10];
    const float* ob    = (const float*)d_in[11];

    float* out = (float*)d_out;
    float* hid = out + 2048000;
    float* att = hid + 65536;
    float* pg     = out;
    float* scores = out;
    float* pm     = out + 65536;
    float* pl     = out + 66560;
    float* pctx   = out + 67584;
    float* ctx    = out + 1116160;
    float* pc     = out + 1181696;
    float* cout_  = (float*)d_ws;

    k1a_gemm<<<dim3(48, 4, 2), 256, 0, stream>>>(idx, lasth, emb, w_ih, w_hh, pg);
    k1b_act<<<256, 256, 0, stream>>>(pg, lasth, b_ih, b_hh, hid);
    k2_attn<<<256, 256, 0, stream>>>(hid, enc, scores, pm, pl, pctx);
    k3_combine<<<64, 256, 0, stream>>>(scores, pm, pl, pctx, ctx, att);
    k4a_gemm<<<dim3(16, 4), 256, 0, stream>>>(hid, ctx, cW, pc);
    k4b_act<<<256, 256, 0, stream>>>(pc, cb, cout_);
    k5_proj<<<500, 256, 0, stream>>>(cout_, oW, ob, out);
}